// Round 10
// baseline (1535.014 us; speedup 1.0000x reference)
//
#include <hip/hip_runtime.h>

#define T_DIM 4096
#define K1    4096      // H (hidden)
#define I_DIM 11008
#define QMAXF 127.0f

typedef int v4i  __attribute__((ext_vector_type(4)));
typedef int v16i __attribute__((ext_vector_type(16)));

// ---------------- helpers ----------------

__device__ __forceinline__ void gload16(const void* g, void* l) {
  __builtin_amdgcn_global_load_lds((__attribute__((address_space(1))) unsigned int*)(g),
                                   (__attribute__((address_space(3))) unsigned int*)(l),
                                   16, 0, 0);
}

__device__ __forceinline__ int packq(float a, float b, float c, float d) {
  return ((int)a & 255) | (((int)b & 255) << 8) | (((int)c & 255) << 16) | (((int)d & 255) << 24);
}

#define MFMA32(A, B, C) __builtin_amdgcn_mfma_i32_32x32x32_i8(A, B, C, 0, 0, 0)

// ---------------- pass 1: absmax(x) ----------------

__global__ void absmax_x_kernel(const float4* __restrict__ x4, unsigned* __restrict__ maxbits, int n4) {
  int tid = blockIdx.x * blockDim.x + threadIdx.x;
  int stride = gridDim.x * blockDim.x;
  float m = 0.f;
  for (int i = tid; i < n4; i += stride) {
    float4 v = x4[i];
    m = fmaxf(m, fmaxf(fmaxf(fabsf(v.x), fabsf(v.y)), fmaxf(fabsf(v.z), fabsf(v.w))));
  }
  #pragma unroll
  for (int off = 32; off; off >>= 1) m = fmaxf(m, __shfl_xor(m, off));
  if ((threadIdx.x & 63) == 0) atomicMax(maxbits, __float_as_uint(m));
}

// ---------------- pass 2: quantize x ----------------

__global__ void quant_x_kernel(const float4* __restrict__ x4, v4i* __restrict__ q4,
                               const unsigned* __restrict__ scal) {
  const float sx = __uint_as_float(scal[0]) * (1.0f / QMAXF);
  const long i = (long)blockIdx.x * blockDim.x + threadIdx.x;  // 16 floats per thread
  v4i o;
  #pragma unroll
  for (int j = 0; j < 4; ++j) {
    float4 v = x4[i * 4 + j];
    float a = fminf(fmaxf(rintf(v.x / sx), -QMAXF), QMAXF);
    float b = fminf(fmaxf(rintf(v.y / sx), -QMAXF), QMAXF);
    float c = fminf(fmaxf(rintf(v.z / sx), -QMAXF), QMAXF);
    float d = fminf(fmaxf(rintf(v.w / sx), -QMAXF), QMAXF);
    o[j] = packq(a, b, c, d);
  }
  q4[i] = o;
}

// ---------------- weight f32(int-valued) -> int8 ----------------

__global__ void conv_w_kernel(const float4* __restrict__ w4, v4i* __restrict__ q4) {
  const long i = (long)blockIdx.x * blockDim.x + threadIdx.x;  // 16 floats per thread
  v4i o;
  #pragma unroll
  for (int j = 0; j < 4; ++j) {
    float4 v = w4[i * 4 + j];
    o[j] = packq(rintf(v.x), rintf(v.y), rintf(v.z), rintf(v.w));
  }
  q4[i] = o;
}

// ================= R5 schedule, half-size tiles, 2 blocks/CU =================
// Tile: 128 out-rows x 256 staged B-rows, BK=64. Ring-3 LDS = 3 x 24576 B = 72 KB
// -> TWO independent blocks per CU (convoy cover via m114 cross-block overlap).
// Per buffer: A [0,8192) = [kslot:4][128 rows][16B]; B [8192,24576) = [kslot:4][256][16B].
// 8 waves (2M x 4N): per-wave 64 rows x 64 staged cols, acc 2x2 v16i (64 regs).
// Per tile: { vmcnt(3) counted; barrier; stage t+2 (3 gloads/thread); 8 ds_read; 8 MFMA }.
// 3-tile unroll -> all ring indices are literals. Race-free: stage for t+2 issues after
// barrier t; buf (t+2)%3's last reads (tile t-1) completed before their MFMAs -> before barrier t.

#define STG3(KO, SB) {                                                      \
    gload16(gA1 + (KO),      &L[SB][lA]);                                   \
    gload16(gB1 + (KO),      &L[SB][lB]);                                   \
    gload16(gB1 + (KO) + 32, &L[SB][lB + 8192]);                            \
  }

#define TILE(U, SB, KO, DOST, VM)                                           \
  {                                                                         \
    asm volatile("s_waitcnt vmcnt(" VM ")" ::: "memory");                   \
    __builtin_amdgcn_s_barrier();                                           \
    asm volatile("" ::: "memory");                                          \
    if (DOST) STG3(KO, SB);                                                 \
    const signed char* Lb = L[(U)];                                         \
    v4i a0 = *(const v4i*)&Lb[kgl * 2048 + ab];                             \
    v4i a1 = *(const v4i*)&Lb[kgl * 2048 + ab + 512];                       \
    v4i b0 = *(const v4i*)&Lb[kgl * 4096 + bb];                             \
    v4i b1 = *(const v4i*)&Lb[kgl * 4096 + bb + 512];                       \
    v4i a2 = *(const v4i*)&Lb[(2 + kgl) * 2048 + ab];                       \
    v4i a3 = *(const v4i*)&Lb[(2 + kgl) * 2048 + ab + 512];                 \
    v4i b2 = *(const v4i*)&Lb[(2 + kgl) * 4096 + bb];                       \
    v4i b3 = *(const v4i*)&Lb[(2 + kgl) * 4096 + bb + 512];                 \
    acc00 = MFMA32(a0, b0, acc00);                                          \
    acc01 = MFMA32(a0, b1, acc01);                                          \
    acc10 = MFMA32(a1, b0, acc10);                                          \
    acc11 = MFMA32(a1, b1, acc11);                                          \
    acc00 = MFMA32(a2, b2, acc00);                                          \
    acc01 = MFMA32(a2, b3, acc01);                                          \
    acc10 = MFMA32(a3, b2, acc10);                                          \
    acc11 = MFMA32(a3, b3, acc11);                                          \
  }

// ---------------- GEMM1 fused: int8 GEMM + dequant + silu*mul + h absmax ----------------
// 256 staged B-rows = 128 h-cols: group g (64 rows) covers h-cols bcol+g*32..+31;
// within group: rows 0..31 = gate, 32..63 = up. Wave wc owns group wc (n0=gate, n1=up).

__global__ __launch_bounds__(512, 4)
void gemm1_silu_kernel(const signed char* __restrict__ qx,
                       const signed char* __restrict__ w8,
                       const float* __restrict__ sgu,
                       unsigned* __restrict__ scal,
                       float* __restrict__ hbuf)
{
  __shared__ signed char L[3][24576];

  const int tid  = threadIdx.x;
  const int lane = tid & 63;
  const int wid  = tid >> 6;       // 0..7
  const int wr   = wid >> 2;       // 0..1  (64-row band)
  const int wc   = wid & 3;        // 0..3  (64 staged-B rows = one gate/up group)
  const int l31  = lane & 31;
  const int kgl  = lane >> 5;

  const int lin = blockIdx.x;                  // 2752 = 8*344
  const int sw  = (lin & 7) * 344 + (lin >> 3);
  const int brow = (sw & 31) * 128;            // 32 row blocks (fastest -> B L2-resident)
  const int bcol = (sw >> 5) * 128;            // 86 col blocks (h-cols)

  // staging: A 1 gload/thread (row tid&127, kslot tid>>7); B 2 gloads (row tid&255, kslots tid>>8, +2)
  const int sra = tid & 127, ska = tid >> 7;
  const signed char* gA1 = qx + (size_t)(brow + sra) * K1 + ska * 16;
  const int sr = tid & 255, sk = tid >> 8;
  const int grp = sr >> 6, w = sr & 63;
  const int gcolw = bcol + grp * 32 + (w & 31);
  const size_t srcrow = (w < 32) ? (size_t)gcolw : (size_t)(I_DIM + gcolw);
  const signed char* gB1 = w8 + srcrow * K1 + sk * 16;
  const int lA = tid * 16;             // A region [0,8192)
  const int lB = 8192 + tid * 16;      // B kslot 0/1; +8192 -> kslot 2/3

  const int ab = (wr * 64 + l31) * 16;                 // + m*512
  const int bb = 8192 + (wc * 64 + l31) * 16;          // + n*512

  v16i acc00 = {0}, acc01 = {0}, acc10 = {0}, acc11 = {0};

  // prologue: stage tiles 0 -> buf0, 1 -> buf1 (3 gloads each)
  STG3(0, 0);
  STG3(64, 1);

  // nk = 64 = 20*3 + 4. Main p=0..19: tiles 3p..3p+2, staging 3p+2..3p+4 (<= 61).
  for (int p = 0; p < 20; ++p) {
    TILE(0, 2, 128, 1, "3")
    TILE(1, 0, 192, 1, "3")
    TILE(2, 1, 256, 1, "3")
    gA1 += 192; gB1 += 192;
  }
  // tail: t=60 (buf0, stage 62->buf2), t=61 (buf1, stage 63->buf0), t=62, t=63
  TILE(0, 2, 128, 1, "3")
  TILE(1, 0, 192, 1, "3")
  TILE(2, 0, 0,   0, "3")
  TILE(0, 0, 0,   0, "0")

  // epilogue: dequant + silu*mul, write h, track max|h|
  // C (32x32): col = l31, row = (q&3) + 8*(q>>2) + 4*kgl  [verified R4/R5]
  const float xsc = __uint_as_float(scal[0]) * (1.0f / QMAXF);
  const int col = bcol + wc * 32 + l31;
  const float sg = sgu[col] * xsc;
  const float su = sgu[I_DIM + col] * xsc;
  float hmax = 0.f;
  #pragma unroll
  for (int m = 0; m < 2; ++m) {
    const int rbase = brow + wr * 64 + m * 32 + 4 * kgl;
    const v16i ag = m ? acc10 : acc00;
    const v16i au = m ? acc11 : acc01;
    #pragma unroll
    for (int q = 0; q < 16; ++q) {
      const int row = rbase + (q & 3) + 8 * (q >> 2);
      float g = (float)ag[q] * sg;
      float u = (float)au[q] * su;
      float hv = (g / (1.f + expf(-g))) * u;
      hmax = fmaxf(hmax, fabsf(hv));
      hbuf[(size_t)row * I_DIM + col] = hv;
    }
  }
  #pragma unroll
  for (int off = 32; off; off >>= 1) hmax = fmaxf(hmax, __shfl_xor(hmax, off));
  if (lane == 0) atomicMax(scal + 1, __float_as_uint(hmax));
}

// ---------------- quantize h (+ emit h_scale) ----------------

__global__ void quant_h_kernel(const float4* __restrict__ h4, v4i* __restrict__ q4,
                               const unsigned* __restrict__ scal, float* __restrict__ hs_out) {
  const float hs = __uint_as_float(scal[1]) * (1.0f / QMAXF);
  const long i = (long)blockIdx.x * blockDim.x + threadIdx.x;
  if (i == 0) hs_out[0] = hs;
  v4i o;
  #pragma unroll
  for (int j = 0; j < 4; ++j) {
    float4 v = h4[i * 4 + j];
    float a = fminf(fmaxf(rintf(v.x / hs), -QMAXF), QMAXF);
    float b = fminf(fmaxf(rintf(v.y / hs), -QMAXF), QMAXF);
    float c = fminf(fmaxf(rintf(v.z / hs), -QMAXF), QMAXF);
    float d = fminf(fmaxf(rintf(v.w / hs), -QMAXF), QMAXF);
    o[j] = packq(a, b, c, d);
  }
  q4[i] = o;
}

// ---------------- GEMM2: out = (qh @ wdn^T) * (h_scale * s_down) ----------------
// Same structure: 128 rows x 256 out-cols, ring-3, 2 blocks/CU. Grid 512 = 8*64.

__global__ __launch_bounds__(512, 4)
void gemm2_kernel(const signed char* __restrict__ qh,
                  const signed char* __restrict__ w8,
                  const float* __restrict__ sdn,
                  const unsigned* __restrict__ scal,
                  float* __restrict__ out)
{
  __shared__ signed char L[3][24576];

  const int tid  = threadIdx.x;
  const int lane = tid & 63;
  const int wid  = tid >> 6;
  const int wr   = wid >> 2;       // 0..1
  const int wc   = wid & 3;        // 0..3
  const int l31  = lane & 31;
  const int kgl  = lane >> 5;

  const int lin = blockIdx.x;                  // 512 = 8*64
  const int sw  = (lin & 7) * 64 + (lin >> 3);
  const int brow = (sw & 31) * 128;
  const int bcol = (sw >> 5) * 256;

  const int sra = tid & 127, ska = tid >> 7;
  const signed char* gA1 = qh + (size_t)(brow + sra) * I_DIM + ska * 16;
  const int sr = tid & 255, sk = tid >> 8;
  const signed char* gB1 = w8 + (size_t)(bcol + sr) * I_DIM + sk * 16;
  const int lA = tid * 16;
  const int lB = 8192 + tid * 16;

  const int ab = (wr * 64 + l31) * 16;
  const int bb = 8192 + (wc * 64 + l31) * 16;

  v16i acc00 = {0}, acc01 = {0}, acc10 = {0}, acc11 = {0};

  STG3(0, 0);
  STG3(64, 1);

  // nk = 172 = 56*3 + 4. Main p=0..55: tiles 3p..3p+2, staging to 169.
  for (int p = 0; p < 56; ++p) {
    TILE(0, 2, 128, 1, "3")
    TILE(1, 0, 192, 1, "3")
    TILE(2, 1, 256, 1, "3")
    gA1 += 192; gB1 += 192;
  }
  // tail: t=168 (buf0, stage 170->buf2), t=169 (buf1, stage 171->buf0), t=170, t=171
  TILE(0, 2, 128, 1, "3")
  TILE(1, 0, 192, 1, "3")
  TILE(2, 0, 0,   0, "3")
  TILE(0, 0, 0,   0, "0")

  const float hsc = __uint_as_float(scal[1]) * (1.0f / QMAXF);
  #pragma unroll
  for (int m = 0; m < 2; ++m) {
    const int rbase = brow + wr * 64 + m * 32 + 4 * kgl;
    #pragma unroll
    for (int n = 0; n < 2; ++n) {
      const int col = bcol + wc * 64 + n * 32 + l31;
      const float s = sdn[col] * hsc;
      const v16i av = m ? (n ? acc11 : acc10) : (n ? acc01 : acc00);
      #pragma unroll
      for (int q = 0; q < 16; ++q) {
        const int row = rbase + (q & 3) + 8 * (q >> 2);
        out[(size_t)row * K1 + col] = (float)av[q] * s;
      }
    }
  }
}

// ---------------- launch ----------------

extern "C" void kernel_launch(void* const* d_in, const int* in_sizes, int n_in,
                              void* d_out, int out_size, void* d_ws, size_t ws_size,
                              hipStream_t stream) {
  (void)in_sizes; (void)n_in; (void)out_size; (void)ws_size;
  const float* x   = (const float*)d_in[0];
  const float* wgu = (const float*)d_in[1];
  const float* sgu = (const float*)d_in[2];
  const float* wdn = (const float*)d_in[3];
  const float* sdn = (const float*)d_in[4];
  float* out = (float*)d_out;
  char* ws = (char*)d_ws;

  // ws layout (16B aligned): total ~360 MB
  signed char* qx  = (signed char*)(ws + 0LL);           // 16,777,216
  signed char* w8g = (signed char*)(ws + 16777216LL);    // 90,177,536
  signed char* w8d = (signed char*)(ws + 106954752LL);   // 45,088,768
  signed char* qh  = (signed char*)(ws + 152043520LL);   // 45,088,768
  float*       hb  = (float*)      (ws + 197132288LL);   // 180,355,072
  unsigned*    scal= (unsigned*)   (ws + 377487360LL);   // 256

  hipMemsetAsync(scal, 0, 256, stream);
  absmax_x_kernel<<<2048, 256, 0, stream>>>((const float4*)x, scal, T_DIM * K1 / 4);
  quant_x_kernel<<<4096, 256, 0, stream>>>((const float4*)x, (v4i*)qx, scal);
  conv_w_kernel<<<22016, 256, 0, stream>>>((const float4*)wgu, (v4i*)w8g);
  conv_w_kernel<<<11008, 256, 0, stream>>>((const float4*)wdn, (v4i*)w8d);

  gemm1_silu_kernel<<<2752, 512, 0, stream>>>(qx, w8g, sgu, scal, hb);

  quant_h_kernel<<<11008, 256, 0, stream>>>((const float4*)hb, (v4i*)qh, scal,
                                            out + (size_t)T_DIM * K1);

  gemm2_kernel<<<512, 512, 0, stream>>>(qh, w8d, sdn, scal, out);
}

// Round 11
// 1158.533 us; speedup vs baseline: 1.3250x; 1.3250x over previous
//
#include <hip/hip_runtime.h>

#define T_DIM 4096
#define K1    4096      // H (hidden)
#define I_DIM 11008
#define QMAXF 127.0f

typedef int v4i  __attribute__((ext_vector_type(4)));
typedef int v16i __attribute__((ext_vector_type(16)));

// ---------------- helpers ----------------

__device__ __forceinline__ void gload16(const void* g, void* l) {
  __builtin_amdgcn_global_load_lds((__attribute__((address_space(1))) unsigned int*)(g),
                                   (__attribute__((address_space(3))) unsigned int*)(l),
                                   16, 0, 0);
}

__device__ __forceinline__ int packq(float a, float b, float c, float d) {
  return ((int)a & 255) | (((int)b & 255) << 8) | (((int)c & 255) << 16) | (((int)d & 255) << 24);
}

#define MFMA32(A, B, C) __builtin_amdgcn_mfma_i32_32x32x32_i8(A, B, C, 0, 0, 0)

// ---------------- pass 1: absmax(x) ----------------

__global__ void absmax_x_kernel(const float4* __restrict__ x4, unsigned* __restrict__ maxbits, int n4) {
  int tid = blockIdx.x * blockDim.x + threadIdx.x;
  int stride = gridDim.x * blockDim.x;
  float m = 0.f;
  for (int i = tid; i < n4; i += stride) {
    float4 v = x4[i];
    m = fmaxf(m, fmaxf(fmaxf(fabsf(v.x), fabsf(v.y)), fmaxf(fabsf(v.z), fabsf(v.w))));
  }
  #pragma unroll
  for (int off = 32; off; off >>= 1) m = fmaxf(m, __shfl_xor(m, off));
  if ((threadIdx.x & 63) == 0) atomicMax(maxbits, __float_as_uint(m));
}

// ---------------- pass 2: quantize x ----------------

__global__ void quant_x_kernel(const float4* __restrict__ x4, v4i* __restrict__ q4,
                               const unsigned* __restrict__ scal) {
  const float sx = __uint_as_float(scal[0]) * (1.0f / QMAXF);
  const long i = (long)blockIdx.x * blockDim.x + threadIdx.x;  // 16 floats per thread
  v4i o;
  #pragma unroll
  for (int j = 0; j < 4; ++j) {
    float4 v = x4[i * 4 + j];
    float a = fminf(fmaxf(rintf(v.x / sx), -QMAXF), QMAXF);
    float b = fminf(fmaxf(rintf(v.y / sx), -QMAXF), QMAXF);
    float c = fminf(fmaxf(rintf(v.z / sx), -QMAXF), QMAXF);
    float d = fminf(fmaxf(rintf(v.w / sx), -QMAXF), QMAXF);
    o[j] = packq(a, b, c, d);
  }
  q4[i] = o;
}

// ---------------- weight f32(int-valued) -> int8 ----------------

__global__ void conv_w_kernel(const float4* __restrict__ w4, v4i* __restrict__ q4) {
  const long i = (long)blockIdx.x * blockDim.x + threadIdx.x;  // 16 floats per thread
  v4i o;
  #pragma unroll
  for (int j = 0; j < 4; ++j) {
    float4 v = w4[i * 4 + j];
    o[j] = packq(rintf(v.x), rintf(v.y), rintf(v.z), rintf(v.w));
  }
  q4[i] = o;
}

// ================= best-known GEMM structure (R5) =================
// 256x256 tile (256 T-rows x 256 staged B-rows), BK=64.
// 512 thr = 8 waves (4M x 2N), per-wave 64 rows x 128 staged cols, acc[2][4] v16i.
// LDS: 4-buffer ring x (A 16KB + B 16KB) = 128 KB. Tile layout [kslot:4][row:256][16B].
// Distance-3 prefetch: while reading tile t, stage tile t+3 into buf (t+3)&3 (fully consumed).
// Steady-state wait = vmcnt(8) (tiles t+1,t+2 in flight), never 0 until drain.
// Per tile 2 phases (ks=0,1): {6x ds_read_b128; 2x gload; barrier; lgkm0; sched_barrier;
//                              prio1; 8 MFMA; prio0}.

// ---------------- GEMM1 fused: int8 GEMM + dequant + silu*mul + h absmax ----------------

__global__ __launch_bounds__(512, 2)
void gemm1_silu_kernel(const signed char* __restrict__ qx,
                       const signed char* __restrict__ w8,
                       const float* __restrict__ sgu,
                       unsigned* __restrict__ scal,
                       float* __restrict__ hbuf)
{
  __shared__ signed char L[4][32768];   // per buf: A [0,16384), B [16384,32768)

  const int tid  = threadIdx.x;
  const int lane = tid & 63;
  const int wid  = tid >> 6;       // 0..7
  const int wr   = wid >> 1;       // 0..3  (64-row band)
  const int wc   = wid & 1;        // 0..1  (128 staged-B rows)
  const int l31  = lane & 31;
  const int kgl  = lane >> 5;

  // XCD-chunked bijective swizzle (1376 = 8*172); brow fastest -> B panel L2-resident
  const int lin = blockIdx.x;
  const int sw  = (lin & 7) * 172 + (lin >> 3);
  const int brow = (sw & 15) * 256;
  const int bcol = (sw >> 4) * 128;            // h-col base (128 per block)

  // staging: thread covers staged row sr=tid&255, sub-kslot sk=tid>>8
  const int sr = tid & 255, sk = tid >> 8;
  const signed char* gA = qx + (size_t)(brow + sr) * K1 + sk * 16;
  const int grp = sr >> 6, w = sr & 63;
  const int gcolw = bcol + grp * 32 + (w & 31);
  const size_t srcrow = (w < 32) ? (size_t)gcolw : (size_t)(I_DIM + gcolw);
  const signed char* gB = w8 + srcrow * K1 + sk * 16;
  const int lA = tid * 16;             // + 8192 for upper kslot pair
  const int lB = 16384 + tid * 16;

  // fragment bases: [kslot][row][16B]; kslot = 2*ks + kgl
  const int ab = (wr * 64 + l31) * 16;
  const int bb = 16384 + (wc * 128 + l31) * 16;

  v16i zero = {0};
  v16i acc[2][4];
  #pragma unroll
  for (int m = 0; m < 2; ++m)
    #pragma unroll
    for (int n = 0; n < 4; ++n) acc[m][n] = zero;

  const int nk = K1 / 64;  // 64
  // prologue: stage tiles 0,1,2 (4 gloads each)
  #pragma unroll
  for (int t = 0; t < 3; ++t) {
    gload16(gA + t * 64,      &L[t][lA]);
    gload16(gA + t * 64 + 32, &L[t][lA + 8192]);
    gload16(gB + t * 64,      &L[t][lB]);
    gload16(gB + t * 64 + 32, &L[t][lB + 8192]);
  }

  for (int t = 0; t < nk; ++t) {
    if (t + 2 < nk)      asm volatile("s_waitcnt vmcnt(8)" ::: "memory");
    else if (t + 1 < nk) asm volatile("s_waitcnt vmcnt(4)" ::: "memory");
    else                 asm volatile("s_waitcnt vmcnt(0)" ::: "memory");
    __builtin_amdgcn_s_barrier();
    asm volatile("" ::: "memory");
    const signed char* Lb = L[t & 3];
    signed char* Ls = L[(t + 3) & 3];
    const bool st = (t + 3) < nk;
    const int ko = (t + 3) * 64;

    // ---- phase 0 (ks=0) ----
    {
      v4i af0, af1, bf0, bf1, bf2, bf3;
      af0 = *(const v4i*)&Lb[kgl * 4096 + ab];
      af1 = *(const v4i*)&Lb[kgl * 4096 + ab + 512];
      bf0 = *(const v4i*)&Lb[kgl * 4096 + bb];
      bf1 = *(const v4i*)&Lb[kgl * 4096 + bb + 512];
      bf2 = *(const v4i*)&Lb[kgl * 4096 + bb + 1024];
      bf3 = *(const v4i*)&Lb[kgl * 4096 + bb + 1536];
      if (st) {
        gload16(gA + ko,      &Ls[lA]);
        gload16(gA + ko + 32, &Ls[lA + 8192]);
      }
      __builtin_amdgcn_s_barrier();
      asm volatile("s_waitcnt lgkmcnt(0)" ::: "memory");
      __builtin_amdgcn_sched_barrier(0);
      __builtin_amdgcn_s_setprio(1);
      acc[0][0] = MFMA32(af0, bf0, acc[0][0]);
      acc[0][1] = MFMA32(af0, bf1, acc[0][1]);
      acc[0][2] = MFMA32(af0, bf2, acc[0][2]);
      acc[0][3] = MFMA32(af0, bf3, acc[0][3]);
      acc[1][0] = MFMA32(af1, bf0, acc[1][0]);
      acc[1][1] = MFMA32(af1, bf1, acc[1][1]);
      acc[1][2] = MFMA32(af1, bf2, acc[1][2]);
      acc[1][3] = MFMA32(af1, bf3, acc[1][3]);
      __builtin_amdgcn_s_setprio(0);
    }

    // ---- phase 1 (ks=1) ----
    {
      v4i af0, af1, bf0, bf1, bf2, bf3;
      af0 = *(const v4i*)&Lb[(2 + kgl) * 4096 + ab];
      af1 = *(const v4i*)&Lb[(2 + kgl) * 4096 + ab + 512];
      bf0 = *(const v4i*)&Lb[(2 + kgl) * 4096 + bb];
      bf1 = *(const v4i*)&Lb[(2 + kgl) * 4096 + bb + 512];
      bf2 = *(const v4i*)&Lb[(2 + kgl) * 4096 + bb + 1024];
      bf3 = *(const v4i*)&Lb[(2 + kgl) * 4096 + bb + 1536];
      if (st) {
        gload16(gB + ko,      &Ls[lB]);
        gload16(gB + ko + 32, &Ls[lB + 8192]);
      }
      __builtin_amdgcn_s_barrier();
      asm volatile("s_waitcnt lgkmcnt(0)" ::: "memory");
      __builtin_amdgcn_sched_barrier(0);
      __builtin_amdgcn_s_setprio(1);
      acc[0][0] = MFMA32(af0, bf0, acc[0][0]);
      acc[0][1] = MFMA32(af0, bf1, acc[0][1]);
      acc[0][2] = MFMA32(af0, bf2, acc[0][2]);
      acc[0][3] = MFMA32(af0, bf3, acc[0][3]);
      acc[1][0] = MFMA32(af1, bf0, acc[1][0]);
      acc[1][1] = MFMA32(af1, bf1, acc[1][1]);
      acc[1][2] = MFMA32(af1, bf2, acc[1][2]);
      acc[1][3] = MFMA32(af1, bf3, acc[1][3]);
      __builtin_amdgcn_s_setprio(0);
    }
  }

  // epilogue: dequant + silu*mul, write h, track max|h|
  // C layout (32x32): col(lane)=l31, row = (q&3) + 8*(q>>2) + 4*kgl
  // n-frag pairs: (0,1)=gate/up @ grp wc*2, (2,3)=gate/up @ grp wc*2+1
  const float xsc = __uint_as_float(scal[0]) * (1.0f / QMAXF);
  float hmax = 0.f;
  #pragma unroll
  for (int m = 0; m < 2; ++m) {
    const int rbase = brow + wr * 64 + m * 32 + 4 * kgl;
    #pragma unroll
    for (int p = 0; p < 2; ++p) {
      const int col = bcol + (wc * 2 + p) * 32 + l31;
      const float sg = sgu[col] * xsc;
      const float su = sgu[I_DIM + col] * xsc;
      #pragma unroll
      for (int q = 0; q < 16; ++q) {
        const int row = rbase + (q & 3) + 8 * (q >> 2);
        float g = (float)acc[m][2 * p][q] * sg;
        float u = (float)acc[m][2 * p + 1][q] * su;
        float hv = (g / (1.f + expf(-g))) * u;
        hmax = fmaxf(hmax, fabsf(hv));
        hbuf[(size_t)row * I_DIM + col] = hv;
      }
    }
  }
  #pragma unroll
  for (int off = 32; off; off >>= 1) hmax = fmaxf(hmax, __shfl_xor(hmax, off));
  if (lane == 0) atomicMax(scal + 1, __float_as_uint(hmax));
}

// ---------------- quantize h (+ emit h_scale) ----------------

__global__ void quant_h_kernel(const float4* __restrict__ h4, v4i* __restrict__ q4,
                               const unsigned* __restrict__ scal, float* __restrict__ hs_out) {
  const float hs = __uint_as_float(scal[1]) * (1.0f / QMAXF);
  const long i = (long)blockIdx.x * blockDim.x + threadIdx.x;
  if (i == 0) hs_out[0] = hs;
  v4i o;
  #pragma unroll
  for (int j = 0; j < 4; ++j) {
    float4 v = h4[i * 4 + j];
    float a = fminf(fmaxf(rintf(v.x / hs), -QMAXF), QMAXF);
    float b = fminf(fmaxf(rintf(v.y / hs), -QMAXF), QMAXF);
    float c = fminf(fmaxf(rintf(v.z / hs), -QMAXF), QMAXF);
    float d = fminf(fmaxf(rintf(v.w / hs), -QMAXF), QMAXF);
    o[j] = packq(a, b, c, d);
  }
  q4[i] = o;
}

// ---------------- GEMM2: out = (qh @ wdn^T) * (h_scale * s_down) ----------------
// 256x256 tile, BK=64, same ring/phase structure as gemm1. Grid 256 = 1 block/CU.

__global__ __launch_bounds__(512, 2)
void gemm2_kernel(const signed char* __restrict__ qh,
                  const signed char* __restrict__ w8,
                  const float* __restrict__ sdn,
                  const unsigned* __restrict__ scal,
                  float* __restrict__ out)
{
  __shared__ signed char L[4][32768];

  const int tid  = threadIdx.x;
  const int lane = tid & 63;
  const int wid  = tid >> 6;
  const int wr   = wid >> 1;       // 0..3
  const int wc   = wid & 1;        // 0..1
  const int l31  = lane & 31;
  const int kgl  = lane >> 5;

  const int lin = blockIdx.x;                  // 0..255 = 8*32
  const int sw  = (lin & 7) * 32 + (lin >> 3);
  const int brow = (sw & 15) * 256;
  const int bcol = (sw >> 4) * 256;

  const int sr = tid & 255, sk = tid >> 8;
  const signed char* gA = qh + (size_t)(brow + sr) * I_DIM + sk * 16;
  const signed char* gB = w8 + (size_t)(bcol + sr) * I_DIM + sk * 16;
  const int lA = tid * 16;
  const int lB = 16384 + tid * 16;

  const int ab = (wr * 64 + l31) * 16;
  const int bb = 16384 + (wc * 128 + l31) * 16;

  v16i zero = {0};
  v16i acc[2][4];
  #pragma unroll
  for (int m = 0; m < 2; ++m)
    #pragma unroll
    for (int n = 0; n < 4; ++n) acc[m][n] = zero;

  const int nk = I_DIM / 64;  // 172
  #pragma unroll
  for (int t = 0; t < 3; ++t) {
    gload16(gA + t * 64,      &L[t][lA]);
    gload16(gA + t * 64 + 32, &L[t][lA + 8192]);
    gload16(gB + t * 64,      &L[t][lB]);
    gload16(gB + t * 64 + 32, &L[t][lB + 8192]);
  }

  for (int t = 0; t < nk; ++t) {
    if (t + 2 < nk)      asm volatile("s_waitcnt vmcnt(8)" ::: "memory");
    else if (t + 1 < nk) asm volatile("s_waitcnt vmcnt(4)" ::: "memory");
    else                 asm volatile("s_waitcnt vmcnt(0)" ::: "memory");
    __builtin_amdgcn_s_barrier();
    asm volatile("" ::: "memory");
    const signed char* Lb = L[t & 3];
    signed char* Ls = L[(t + 3) & 3];
    const bool st = (t + 3) < nk;
    const int ko = (t + 3) * 64;

    // ---- phase 0 (ks=0) ----
    {
      v4i af0, af1, bf0, bf1, bf2, bf3;
      af0 = *(const v4i*)&Lb[kgl * 4096 + ab];
      af1 = *(const v4i*)&Lb[kgl * 4096 + ab + 512];
      bf0 = *(const v4i*)&Lb[kgl * 4096 + bb];
      bf1 = *(const v4i*)&Lb[kgl * 4096 + bb + 512];
      bf2 = *(const v4i*)&Lb[kgl * 4096 + bb + 1024];
      bf3 = *(const v4i*)&Lb[kgl * 4096 + bb + 1536];
      if (st) {
        gload16(gA + ko,      &Ls[lA]);
        gload16(gA + ko + 32, &Ls[lA + 8192]);
      }
      __builtin_amdgcn_s_barrier();
      asm volatile("s_waitcnt lgkmcnt(0)" ::: "memory");
      __builtin_amdgcn_sched_barrier(0);
      __builtin_amdgcn_s_setprio(1);
      acc[0][0] = MFMA32(af0, bf0, acc[0][0]);
      acc[0][1] = MFMA32(af0, bf1, acc[0][1]);
      acc[0][2] = MFMA32(af0, bf2, acc[0][2]);
      acc[0][3] = MFMA32(af0, bf3, acc[0][3]);
      acc[1][0] = MFMA32(af1, bf0, acc[1][0]);
      acc[1][1] = MFMA32(af1, bf1, acc[1][1]);
      acc[1][2] = MFMA32(af1, bf2, acc[1][2]);
      acc[1][3] = MFMA32(af1, bf3, acc[1][3]);
      __builtin_amdgcn_s_setprio(0);
    }

    // ---- phase 1 (ks=1) ----
    {
      v4i af0, af1, bf0, bf1, bf2, bf3;
      af0 = *(const v4i*)&Lb[(2 + kgl) * 4096 + ab];
      af1 = *(const v4i*)&Lb[(2 + kgl) * 4096 + ab + 512];
      bf0 = *(const v4i*)&Lb[(2 + kgl) * 4096 + bb];
      bf1 = *(const v4i*)&Lb[(2 + kgl) * 4096 + bb + 512];
      bf2 = *(const v4i*)&Lb[(2 + kgl) * 4096 + bb + 1024];
      bf3 = *(const v4i*)&Lb[(2 + kgl) * 4096 + bb + 1536];
      if (st) {
        gload16(gB + ko,      &Ls[lB]);
        gload16(gB + ko + 32, &Ls[lB + 8192]);
      }
      __builtin_amdgcn_s_barrier();
      asm volatile("s_waitcnt lgkmcnt(0)" ::: "memory");
      __builtin_amdgcn_sched_barrier(0);
      __builtin_amdgcn_s_setprio(1);
      acc[0][0] = MFMA32(af0, bf0, acc[0][0]);
      acc[0][1] = MFMA32(af0, bf1, acc[0][1]);
      acc[0][2] = MFMA32(af0, bf2, acc[0][2]);
      acc[0][3] = MFMA32(af0, bf3, acc[0][3]);
      acc[1][0] = MFMA32(af1, bf0, acc[1][0]);
      acc[1][1] = MFMA32(af1, bf1, acc[1][1]);
      acc[1][2] = MFMA32(af1, bf2, acc[1][2]);
      acc[1][3] = MFMA32(af1, bf3, acc[1][3]);
      __builtin_amdgcn_s_setprio(0);
    }
  }

  const float hsc = __uint_as_float(scal[1]) * (1.0f / QMAXF);
  #pragma unroll
  for (int m = 0; m < 2; ++m) {
    const int rbase = brow + wr * 64 + m * 32 + 4 * kgl;
    #pragma unroll
    for (int n = 0; n < 4; ++n) {
      const int col = bcol + wc * 128 + n * 32 + l31;
      const float s = sdn[col] * hsc;
      #pragma unroll
      for (int q = 0; q < 16; ++q) {
        const int row = rbase + (q & 3) + 8 * (q >> 2);
        out[(size_t)row * K1 + col] = (float)acc[m][n][q] * s;
      }
    }
  }
}

// ---------------- launch ----------------

extern "C" void kernel_launch(void* const* d_in, const int* in_sizes, int n_in,
                              void* d_out, int out_size, void* d_ws, size_t ws_size,
                              hipStream_t stream) {
  (void)in_sizes; (void)n_in; (void)out_size; (void)ws_size;
  const float* x   = (const float*)d_in[0];
  const float* wgu = (const float*)d_in[1];
  const float* sgu = (const float*)d_in[2];
  const float* wdn = (const float*)d_in[3];
  const float* sdn = (const float*)d_in[4];
  float* out = (float*)d_out;
  char* ws = (char*)d_ws;

  // ws layout (16B aligned): total ~360 MB
  signed char* qx  = (signed char*)(ws + 0LL);           // 16,777,216
  signed char* w8g = (signed char*)(ws + 16777216LL);    // 90,177,536
  signed char* w8d = (signed char*)(ws + 106954752LL);   // 45,088,768
  signed char* qh  = (signed char*)(ws + 152043520LL);   // 45,088,768
  float*       hb  = (float*)      (ws + 197132288LL);   // 180,355,072
  unsigned*    scal= (unsigned*)   (ws + 377487360LL);   // 256

  hipMemsetAsync(scal, 0, 256, stream);
  absmax_x_kernel<<<2048, 256, 0, stream>>>((const float4*)x, scal, T_DIM * K1 / 4);
  quant_x_kernel<<<4096, 256, 0, stream>>>((const float4*)x, (v4i*)qx, scal);
  conv_w_kernel<<<22016, 256, 0, stream>>>((const float4*)wgu, (v4i*)w8g);
  conv_w_kernel<<<11008, 256, 0, stream>>>((const float4*)wdn, (v4i*)w8d);

  gemm1_silu_kernel<<<1376, 512, 0, stream>>>(qx, w8g, sgu, scal, hb);

  quant_h_kernel<<<11008, 256, 0, stream>>>((const float4*)hb, (v4i*)qh, scal,
                                            out + (size_t)T_DIM * K1);

  gemm2_kernel<<<256, 512, 0, stream>>>(qh, w8d, sdn, scal, out);
}